// Round 4
// baseline (267.398 us; speedup 1.0000x reference)
//
#include <hip/hip_runtime.h>
#include <hip/hip_bf16.h>

#define NB 256      // batch
#define NA 64       // atoms
#define NG 978      // genes
#define CELL_IN 978
#define DOSE_IN 12
#define GLOBAL_F 306
#define EXP_IN 434
#define NE 4

// ---- workspace layout (float offsets) ----
#define WS_G      0                         // g_feat  [256*306]
#define WS_GATES  (WS_G + NB*GLOBAL_F)      // gates   [256*4]
#define WS_U      (WS_GATES + NB*NE)        // u       [256*4*128]
#define WS_V      (WS_U + NB*NE*128)        // v       [978*4*128]
#define WS_H1     (WS_V + NG*NE*128)        // h1      [256*200]
#define WS_GH     (WS_H1 + NB*200)          // gh      [256*128]
#define WS_W1T    (WS_GH + NB*128)          // W1T     [200*978]
#define WS_GW1T   (WS_W1T + 200*CELL_IN)    // gW1T    [128*306]
#define WS_W2T    (WS_GW1T + 128*GLOBAL_F)  // W2T     [100*200]
#define WS_W3T    (WS_W2T + 100*200)        // W3T     [50*100]
#define WS_EW1T   (WS_W3T + 50*100)         // eW1T_u  [4*128*306]
#define WS_TOTAL  (WS_EW1T + NE*128*GLOBAL_F)   // ~1.21M floats ~4.85 MB

// ---- F1 grid partition (BUGFIX r3->r4: v branch is 1956 blocks, not 3912) ----
#define F1_DRUG_END   128                   // 128 blocks: drug sum
#define F1_DOSE_END   384                   // 256 blocks: dose encoder
#define F1_V_END      (F1_DOSE_END + (NG*NE)/2)          // 1956 blocks, 2 pairs each
#define F1_W1T_END    (F1_V_END + (200*CELL_IN + 255)/256)      // 765
#define F1_GW1T_END   (F1_W1T_END + (128*GLOBAL_F + 255)/256)   // 153
#define F1_W2T_END    (F1_GW1T_END + (100*200 + 255)/256)       // 79
#define F1_W3T_END    (F1_W2T_END + (50*100 + 255)/256)         // 20
#define F1_GRID       (F1_W3T_END + (NE*128*GLOBAL_F)/256)      // +612 = 3969

__device__ __forceinline__ float wave_reduce(float p) {
    #pragma unroll
    for (int off = 32; off > 0; off >>= 1) p += __shfl_down(p, off, 64);
    return p;
}

// ---------------------------------------------------------------------------
// F1: all input-independent work, block-partitioned.
// ---------------------------------------------------------------------------
__global__ __launch_bounds__(256) void f1_kernel(
    const float* __restrict__ drug, const float* __restrict__ idose,
    const float* __restrict__ dW1, const float* __restrict__ db1,
    const float* __restrict__ dW2, const float* __restrict__ db2,
    const float* __restrict__ gene, const float* __restrict__ eW1,
    const float* __restrict__ cW1, const float* __restrict__ gW1,
    const float* __restrict__ cW2, const float* __restrict__ cW3,
    float* __restrict__ ws)
{
    __shared__ float smem[64];
    __shared__ float s_ge[2][128];
    const int blk = blockIdx.x, tid = threadIdx.x;
    float* g_feat = ws + WS_G;
    float* v      = ws + WS_V;

    if (blk < F1_DRUG_END) {                 // ---- drug sum ----
        int t = blk * 256 + tid;             // t < 32768
        int b = t >> 7, d = t & 127;
        float acc = 0.f;
        const float* p = drug + (size_t)b * NA * 128 + d;
        #pragma unroll 8
        for (int a = 0; a < NA; ++a) acc += p[a * 128];
        g_feat[b * GLOBAL_F + d] = acc;
    } else if (blk < F1_DOSE_END) {          // ---- dose encoder ----
        int b = blk - F1_DRUG_END;
        if (tid < 64) {
            float acc = db1[tid];
            #pragma unroll
            for (int i = 0; i < DOSE_IN; ++i)
                acc += idose[b * DOSE_IN + i] * dW1[i * 64 + tid];
            smem[tid] = fmaxf(acc, 0.f);
        }
        __syncthreads();
        if (tid < 128) {
            float acc = db2[tid];
            for (int i = 0; i < 64; ++i)
                acc += smem[i] * dW2[i * 128 + tid];
            g_feat[b * GLOBAL_F + 178 + tid] = fmaxf(acc, 0.f);
        }
    } else if (blk < F1_V_END) {             // ---- v GEMM (2 (g,e) pairs/block) ----
        int geb = (blk - F1_DOSE_END) * 2 + (tid >> 7);   // geb < 3912
        int g = geb >> 2, e = geb & 3, h = tid & 127;
        s_ge[tid >> 7][h] = gene[g * 128 + h];
        __syncthreads();
        float acc = 0.f;
        const float* w = eW1 + ((size_t)e * EXP_IN + GLOBAL_F) * 128 + h;
        for (int i = 0; i < 128; ++i) acc += s_ge[tid >> 7][i] * w[i * 128];
        v[(size_t)geb * 128 + h] = acc;
    } else if (blk < F1_W1T_END) {           // ---- W1T [200][978] ----
        int o = (blk - F1_V_END) * 256 + tid;
        if (o < 200 * CELL_IN) {
            int j = o / CELL_IN, i = o % CELL_IN;
            ws[WS_W1T + o] = cW1[i * 200 + j];
        }
    } else if (blk < F1_GW1T_END) {          // ---- gW1T [128][306] ----
        int o = (blk - F1_W1T_END) * 256 + tid;
        if (o < 128 * GLOBAL_F) {
            int j = o / GLOBAL_F, i = o % GLOBAL_F;
            ws[WS_GW1T + o] = gW1[i * 128 + j];
        }
    } else if (blk < F1_W2T_END) {           // ---- W2T [100][200] ----
        int o = (blk - F1_GW1T_END) * 256 + tid;
        if (o < 100 * 200) {
            int j = o / 200, i = o % 200;
            ws[WS_W2T + o] = cW2[i * 100 + j];
        }
    } else if (blk < F1_W3T_END) {           // ---- W3T [50][100] ----
        int o = (blk - F1_W2T_END) * 256 + tid;
        if (o < 50 * 100) {
            int j = o / 100, i = o % 100;
            ws[WS_W3T + o] = cW3[i * 50 + j];
        }
    } else {                                 // ---- eW1T [4][128][306] ----
        int o = (blk - F1_W3T_END) * 256 + tid;
        if (o < NE * 128 * GLOBAL_F) {
            int i = o % GLOBAL_F;
            int eh = o / GLOBAL_F;
            int h = eh & 127, e = eh >> 7;
            ws[WS_EW1T + o] = eW1[((size_t)e * EXP_IN + i) * 128 + h];
        }
    }
}

// ---------------------------------------------------------------------------
// F2: cell layer1 tiled GEMM  h1[b,j] = relu(gex[b,:] @ cW1[:,j] + cb1[j])
// M=256, N=200, K=978; 16x16 tile per block, K-chunks of 64 in LDS.
// grid = 16 (M-tiles) x 13 (N-tiles) = 208 blocks
// ---------------------------------------------------------------------------
__global__ __launch_bounds__(256) void f2_cell1(
    const float* __restrict__ gex, const float* __restrict__ cb1,
    float* __restrict__ ws)
{
    __shared__ float s_A[16][65];
    __shared__ float s_B[16][65];
    const float* W1T = ws + WS_W1T;
    float* h1 = ws + WS_H1;

    const int bx = blockIdx.x % 13, by = blockIdx.x / 13, tid = threadIdx.x;
    const int tx = tid & 15, ty = tid >> 4;
    const int j = bx * 16 + tx, b = by * 16 + ty;

    float acc = 0.f;
    for (int kc = 0; kc < 16; ++kc) {
        for (int idx = tid; idx < 16 * 64; idx += 256) {
            int r = idx >> 6, c = idx & 63, k = kc * 64 + c;
            s_A[r][c] = (k < CELL_IN) ? gex[(by * 16 + r) * CELL_IN + k] : 0.f;
            int jr = bx * 16 + r;
            s_B[r][c] = (k < CELL_IN && jr < 200) ? W1T[jr * CELL_IN + k] : 0.f;
        }
        __syncthreads();
        #pragma unroll 16
        for (int kk = 0; kk < 64; ++kk)
            acc += s_A[ty][kk] * s_B[tx][kk];
        __syncthreads();
    }
    if (j < 200) h1[b * 200 + j] = fmaxf(acc + cb1[j], 0.f);
}

// ---------------------------------------------------------------------------
// F3: cell layers 2+3, wave-per-output. One block per batch.
// ---------------------------------------------------------------------------
__global__ __launch_bounds__(256) void f3_cell23(
    const float* __restrict__ cb2, const float* __restrict__ cb3,
    float* __restrict__ ws, float* __restrict__ cell_out)
{
    __shared__ float s_h1[200];
    __shared__ float s_h2[100];
    const float* W2T = ws + WS_W2T;
    const float* W3T = ws + WS_W3T;
    const float* h1  = ws + WS_H1;
    float* g_feat = ws + WS_G;

    const int b = blockIdx.x, tid = threadIdx.x;
    const int w = tid >> 6, lane = tid & 63;

    for (int i = tid; i < 200; i += 256) s_h1[i] = h1[b * 200 + i];
    __syncthreads();

    // layer2: 100 outputs, 4 waves x 25
    for (int n = 0; n < 25; ++n) {
        int j = w * 25 + n;
        float p = 0.f;
        #pragma unroll
        for (int k = 0; k < 4; ++k) {
            int i = lane + 64 * k;
            if (i < 200) p += s_h1[i] * W2T[j * 200 + i];
        }
        p = wave_reduce(p);
        if (lane == 0) s_h2[j] = fmaxf(p + cb2[j], 0.f);
    }
    __syncthreads();

    // layer3: 50 outputs, waves 0-1 x 25
    if (w < 2) {
        for (int n = 0; n < 25; ++n) {
            int j = w * 25 + n;
            float p = 0.f;
            #pragma unroll
            for (int k = 0; k < 2; ++k) {
                int i = lane + 64 * k;
                if (i < 100) p += s_h2[i] * W3T[j * 100 + i];
            }
            p = wave_reduce(p);
            if (lane == 0) {
                float r = fmaxf(p + cb3[j], 0.f);
                g_feat[b * GLOBAL_F + 128 + j] = r;
                cell_out[b * 50 + j] = r;
            }
        }
    }
}

// ---------------------------------------------------------------------------
// F4: gate hidden (blocks [0,256)) + u (blocks [256,1280)), wave-per-output.
// ---------------------------------------------------------------------------
__global__ __launch_bounds__(256) void f4_gate1_u(
    const float* __restrict__ gb1, const float* __restrict__ eb1,
    float* __restrict__ ws)
{
    __shared__ float s_g[GLOBAL_F];
    const float* g_feat = ws + WS_G;
    const float* gW1T   = ws + WS_GW1T;
    const float* eW1T   = ws + WS_EW1T;
    float* gh = ws + WS_GH;
    float* u  = ws + WS_U;

    const int blk = blockIdx.x, tid = threadIdx.x;
    const int w = tid >> 6, lane = tid & 63;

    if (blk < 256) {                        // ---- gate hidden: 306 -> 128 relu
        int b = blk;
        for (int i = tid; i < GLOBAL_F; i += 256) s_g[i] = g_feat[b * GLOBAL_F + i];
        __syncthreads();
        for (int n = 0; n < 32; ++n) {
            int j = w * 32 + n;
            float p = 0.f;
            #pragma unroll
            for (int k = 0; k < 5; ++k) {
                int i = lane + 64 * k;
                if (i < GLOBAL_F) p += s_g[i] * gW1T[j * GLOBAL_F + i];
            }
            p = wave_reduce(p);
            if (lane == 0) gh[b * 128 + j] = fmaxf(p + gb1[j], 0.f);
        }
    } else {                                // ---- u[b,e,h] (no relu)
        int be = blk - 256, b = be >> 2, e = be & 3;
        for (int i = tid; i < GLOBAL_F; i += 256) s_g[i] = g_feat[b * GLOBAL_F + i];
        __syncthreads();
        const float* wt = eW1T + (size_t)e * 128 * GLOBAL_F;
        for (int n = 0; n < 32; ++n) {
            int h = w * 32 + n;
            float p = 0.f;
            #pragma unroll
            for (int k = 0; k < 5; ++k) {
                int i = lane + 64 * k;
                if (i < GLOBAL_F) p += s_g[i] * wt[h * GLOBAL_F + i];
            }
            p = wave_reduce(p);
            if (lane == 0) u[(size_t)be * 128 + h] = p + eb1[e * 128 + h];
        }
    }
}

// ---------------------------------------------------------------------------
// F5: gate logits (128 -> 4) + top-2 softmax. One wave per batch.
// ---------------------------------------------------------------------------
__global__ __launch_bounds__(64) void f5_gate2(
    const float* __restrict__ gW2, const float* __restrict__ gb2,
    float* __restrict__ ws)
{
    const float* gh = ws + WS_GH;
    float* gates = ws + WS_GATES;
    const int b = blockIdx.x, lane = threadIdx.x;

    float h0 = gh[b * 128 + lane], h1 = gh[b * 128 + 64 + lane];
    float logit[NE];
    #pragma unroll
    for (int j = 0; j < NE; ++j) {
        float p = h0 * gW2[lane * NE + j] + h1 * gW2[(lane + 64) * NE + j];
        p = wave_reduce(p);
        logit[j] = p + gb2[j];
    }
    if (lane == 0) {
        int i1 = 0; float v1 = logit[0];
        #pragma unroll
        for (int i = 1; i < NE; ++i) if (logit[i] > v1) { v1 = logit[i]; i1 = i; }
        int i2 = -1; float v2 = -__builtin_inff();
        #pragma unroll
        for (int i = 0; i < NE; ++i) {
            if (i == i1) continue;
            if (logit[i] > v2) { v2 = logit[i]; i2 = i; }
        }
        float e2 = __expf(v2 - v1);
        float inv = 1.f / (1.f + e2);
        float out[NE] = {0.f, 0.f, 0.f, 0.f};
        out[i1] = inv; out[i2] = e2 * inv;
        #pragma unroll
        for (int i = 0; i < NE; ++i) gates[b * NE + i] = out[i];
    }
}

// ---------------------------------------------------------------------------
// F6: pred[b,g] = sum_e gates[b,e]*(dot(relu(u[b,e]+v[g,e]), w2[e]) + b2[e])
// grid = B*2 blocks (g split in halves), 256 threads.
// ---------------------------------------------------------------------------
__global__ __launch_bounds__(256) void f6_final(
    const float* __restrict__ eW2, const float* __restrict__ eb2,
    const float* __restrict__ ws, float* __restrict__ pred)
{
    __shared__ float s_u[NE * 128];
    __shared__ float s_w2[NE * 128];
    __shared__ float s_gate[NE];
    __shared__ float s_b2[NE];
    const float* u = ws + WS_U;
    const float* v = ws + WS_V;
    const float* gates = ws + WS_GATES;

    const int b = blockIdx.x >> 1, half = blockIdx.x & 1, tid = threadIdx.x;

    for (int k = tid; k < NE * 128; k += 256) {
        s_u[k]  = u[(size_t)b * NE * 128 + k];
        s_w2[k] = eW2[k];
    }
    if (tid < NE) { s_gate[tid] = gates[b * NE + tid]; s_b2[tid] = eb2[tid]; }
    __syncthreads();

    const int g_lo = half * 489, g_hi = g_lo + 489;
    for (int g = g_lo + tid; g < g_hi; g += 256) {
        float acc = 0.f;
        #pragma unroll
        for (int e = 0; e < NE; ++e) {
            float ge = s_gate[e];
            if (ge != 0.f) {             // block-uniform branch
                const float4* vp = (const float4*)(v + ((size_t)g * NE + e) * 128);
                const float* up = s_u + e * 128;
                const float* wp = s_w2 + e * 128;
                float dot = 0.f;
                #pragma unroll
                for (int k = 0; k < 32; ++k) {
                    float4 vv = vp[k];
                    float t0 = fmaxf(up[4*k+0] + vv.x, 0.f);
                    float t1 = fmaxf(up[4*k+1] + vv.y, 0.f);
                    float t2 = fmaxf(up[4*k+2] + vv.z, 0.f);
                    float t3 = fmaxf(up[4*k+3] + vv.w, 0.f);
                    dot += t0 * wp[4*k+0] + t1 * wp[4*k+1]
                         + t2 * wp[4*k+2] + t3 * wp[4*k+3];
                }
                acc += ge * (dot + s_b2[e]);
            }
        }
        pred[b * NG + g] = acc;
    }
}

// ---------------------------------------------------------------------------
extern "C" void kernel_launch(void* const* d_in, const int* in_sizes, int n_in,
                              void* d_out, int out_size, void* d_ws, size_t ws_size,
                              hipStream_t stream) {
    const float* drug  = (const float*)d_in[0];
    const float* gex   = (const float*)d_in[1];
    const float* idose = (const float*)d_in[2];
    const float* cW1 = (const float*)d_in[3];  const float* cb1 = (const float*)d_in[4];
    const float* cW2 = (const float*)d_in[5];  const float* cb2 = (const float*)d_in[6];
    const float* cW3 = (const float*)d_in[7];  const float* cb3 = (const float*)d_in[8];
    const float* dW1 = (const float*)d_in[9];  const float* db1 = (const float*)d_in[10];
    const float* dW2 = (const float*)d_in[11]; const float* db2 = (const float*)d_in[12];
    const float* gene = (const float*)d_in[13];
    const float* gW1 = (const float*)d_in[14]; const float* gb1 = (const float*)d_in[15];
    const float* gW2 = (const float*)d_in[16]; const float* gb2 = (const float*)d_in[17];
    const float* eW1 = (const float*)d_in[18]; const float* eb1 = (const float*)d_in[19];
    const float* eW2 = (const float*)d_in[20]; const float* eb2 = (const float*)d_in[21];

    float* ws = (float*)d_ws;        // needs WS_TOTAL*4 ≈ 4.9 MB
    float* out  = (float*)d_out;
    float* pred = out;               // [B, G]
    float* cell = out + NB * NG;     // [B, 50]

    f1_kernel<<<F1_GRID, 256, 0, stream>>>(drug, idose, dW1, db1, dW2, db2,
                                           gene, eW1, cW1, gW1, cW2, cW3, ws);
    f2_cell1 <<<16 * 13, 256, 0, stream>>>(gex, cb1, ws);
    f3_cell23<<<NB, 256, 0, stream>>>(cb2, cb3, ws, cell);
    f4_gate1_u<<<256 + NB * NE, 256, 0, stream>>>(gb1, eb1, ws);
    f5_gate2 <<<NB, 64, 0, stream>>>(gW2, gb2, ws);
    f6_final <<<NB * 2, 256, 0, stream>>>(eW2, eb2, ws, pred);
}

// Round 6
// 254.321 us; speedup vs baseline: 1.0514x; 1.0514x over previous
//
#include <hip/hip_runtime.h>

#define NB 256
#define NA 64
#define NG 978
#define CELL_IN 978
#define DOSE_IN 12
#define GLOBAL_F 306
#define EXP_IN 434
#define NE 4

// ---- workspace layout (float offsets) ----
#define WS_GATES 0                        // [256*4]
#define WS_CELL  (WS_GATES + NB*NE)       // [256*50]
#define WS_DOSE  (WS_CELL + NB*50)        // [256*128]
#define WS_PDRUG (WS_DOSE + NB*128)       // [4][256][128] drug partials
#define WS_V     (WS_PDRUG + 4*NB*128)    // [978][4][128]
// total ~678k floats ~2.7 MB

#define K1_V_BLOCKS    128
#define K1_DRUG_BLOCKS 1024
#define K1_GRID        (K1_V_BLOCKS + K1_DRUG_BLOCKS + NB)
#define K1_DYN_LDS     ((64*128 + 128*64) * 4)   // 64 KB

__device__ __forceinline__ float wave_reduce(float p) {
    #pragma unroll
    for (int off = 32; off > 0; off >>= 1) p += __shfl_down(p, off, 64);
    return p;
}

// ---------------------------------------------------------------------------
// K1: v tiled GEMM  +  drug partial sums  +  dose encoder
// ---------------------------------------------------------------------------
__global__ __launch_bounds__(256) void k1_kernel(
    const float* __restrict__ gene, const float* __restrict__ eW1,
    const float* __restrict__ drug, const float* __restrict__ idose,
    const float* __restrict__ dW1, const float* __restrict__ db1,
    const float* __restrict__ dW2, const float* __restrict__ db2,
    float* __restrict__ ws)
{
    extern __shared__ float dyn[];
    const int blk = blockIdx.x, tid = threadIdx.x;

    if (blk < K1_V_BLOCKS) {
        // ---- v[g,e,h] = gene[g,:] @ eW1[e,306:434,:] ----
        // GEMM M=978 N=512(e,h) K=128. 64x64 tile, 4x4 microtile.
        float* sA = dyn;              // [64][128]  gene rows
        float* sB = dyn + 64 * 128;   // [128][64]  weight cols
        const int gt = blk >> 3, nt = blk & 7;
        const int e = nt >> 1, hh = (nt & 1) * 64;

        for (int t = tid; t < 64 * 128; t += 256) {
            int r = t >> 7, c = t & 127, g = gt * 64 + r;
            sA[t] = (g < NG) ? gene[g * 128 + c] : 0.f;
        }
        for (int t = tid; t < 128 * 64; t += 256) {
            int k = t >> 6, h = t & 63;
            sB[t] = eW1[((size_t)e * EXP_IN + GLOBAL_F + k) * 128 + hh + h];
        }
        __syncthreads();

        const int ty = tid >> 4, tx = tid & 15;
        const int r0 = ty * 4, c0 = tx * 4;
        float acc[4][4] = {};
        #pragma unroll 4
        for (int k = 0; k < 128; ++k) {
            float aa[4];
            #pragma unroll
            for (int i = 0; i < 4; ++i) aa[i] = sA[(r0 + i) * 128 + k];
            float4 b4 = *(const float4*)(sB + k * 64 + c0);
            float bb[4] = {b4.x, b4.y, b4.z, b4.w};
            #pragma unroll
            for (int i = 0; i < 4; ++i)
                #pragma unroll
                for (int j = 0; j < 4; ++j) acc[i][j] += aa[i] * bb[j];
        }
        float* v = ws + WS_V;
        #pragma unroll
        for (int i = 0; i < 4; ++i) {
            int g = gt * 64 + r0 + i;
            if (g < NG) {
                float4 o = make_float4(acc[i][0], acc[i][1], acc[i][2], acc[i][3]);
                *(float4*)(v + ((size_t)(g * NE + e)) * 128 + hh + c0) = o;
            }
        }
    } else if (blk < K1_V_BLOCKS + K1_DRUG_BLOCKS) {
        // ---- drug partials: block=(b,q), 16 atoms each -> P[q][b][0:128] ----
        int db = blk - K1_V_BLOCKS;
        int b = db >> 2, q = db & 3;
        int d = tid & 127, row = tid >> 7;
        const float* p = drug + ((size_t)(b * NA + q * 16 + row * 8)) * 128 + d;
        float acc = 0.f;
        #pragma unroll
        for (int a = 0; a < 8; ++a) acc += p[a * 128];
        dyn[tid] = acc;
        __syncthreads();
        if (tid < 128)
            ws[WS_PDRUG + ((q * NB + b) * 128) + tid] = dyn[tid] + dyn[128 + tid];
    } else {
        // ---- dose encoder: 12 -> 64 -> 128 ----
        int b = blk - (K1_V_BLOCKS + K1_DRUG_BLOCKS);
        float* s_d1 = dyn;
        if (tid < 64) {
            float acc = db1[tid];
            #pragma unroll
            for (int i = 0; i < DOSE_IN; ++i)
                acc += idose[b * DOSE_IN + i] * dW1[i * 64 + tid];
            s_d1[tid] = fmaxf(acc, 0.f);
        }
        __syncthreads();
        if (tid < 128) {
            float acc = db2[tid];
            for (int i = 0; i < 64; ++i)
                acc += s_d1[i] * dW2[i * 128 + tid];
            ws[WS_DOSE + b * 128 + tid] = fmaxf(acc, 0.f);
        }
    }
}

// ---------------------------------------------------------------------------
// K2: per-batch cell chain 978->200->100->50  +  gate MLP + top-2 softmax.
// 512 threads: 2-way K-split on the long dot products.
// ---------------------------------------------------------------------------
__global__ __launch_bounds__(512) void k2_kernel(
    const float* __restrict__ gex,
    const float* __restrict__ cW1, const float* __restrict__ cb1,
    const float* __restrict__ cW2, const float* __restrict__ cb2,
    const float* __restrict__ cW3, const float* __restrict__ cb3,
    const float* __restrict__ gW1, const float* __restrict__ gb1,
    const float* __restrict__ gW2, const float* __restrict__ gb2,
    float* __restrict__ ws, float* __restrict__ cell_out)
{
    __shared__ float s_gex[CELL_IN];
    __shared__ float s_g[GLOBAL_F];
    __shared__ float s_h1[200];
    __shared__ float s_h2[100];
    __shared__ float s_gh[128];
    __shared__ float s_part[512];

    const int b = blockIdx.x, tid = threadIdx.x;

    // phase 0: stage gex row + drug/dose parts of g
    for (int i = tid; i < CELL_IN; i += 512) s_gex[i] = gex[b * CELL_IN + i];
    if (tid < 128) {
        float a = ws[WS_PDRUG + (0 * NB + b) * 128 + tid]
                + ws[WS_PDRUG + (1 * NB + b) * 128 + tid]
                + ws[WS_PDRUG + (2 * NB + b) * 128 + tid]
                + ws[WS_PDRUG + (3 * NB + b) * 128 + tid];
        s_g[tid] = a;
    } else if (tid < 256) {
        int d = tid - 128;
        s_g[178 + d] = ws[WS_DOSE + b * 128 + d];
    }
    __syncthreads();

    // phase 1: cell layer1 978 -> 200, 2-way K-split
    {
        int jj = tid & 255, ks = tid >> 8;
        if (jj < 200) {
            float acc = ks ? 0.f : cb1[jj];
            int i0 = ks * 489;
            #pragma unroll 8
            for (int i = i0; i < i0 + 489; ++i)
                acc += s_gex[i] * cW1[i * 200 + jj];
            s_part[ks * 256 + jj] = acc;
        }
    }
    __syncthreads();
    if (tid < 200) s_h1[tid] = fmaxf(s_part[tid] + s_part[256 + tid], 0.f);
    __syncthreads();

    // phase 2: cell layer2 200 -> 100, 2-way K-split
    {
        int jj = tid & 255, ks = tid >> 8;
        if (jj < 100) {
            float acc = ks ? 0.f : cb2[jj];
            int i0 = ks * 100;
            #pragma unroll 8
            for (int i = i0; i < i0 + 100; ++i)
                acc += s_h1[i] * cW2[i * 100 + jj];
            s_part[ks * 256 + jj] = acc;
        }
    }
    __syncthreads();
    if (tid < 100) s_h2[tid] = fmaxf(s_part[tid] + s_part[256 + tid], 0.f);
    __syncthreads();

    // phase 3: cell layer3 100 -> 50
    if (tid < 50) {
        float acc = cb3[tid];
        #pragma unroll 8
        for (int i = 0; i < 100; ++i)
            acc += s_h2[i] * cW3[i * 50 + tid];
        float r = fmaxf(acc, 0.f);
        s_g[128 + tid] = r;
        ws[WS_CELL + b * 50 + tid] = r;
        cell_out[b * 50 + tid] = r;
    }
    __syncthreads();

    // phase 4: gate hidden 306 -> 128, 2-way K-split
    if (tid < 256) {
        int j = tid & 127, ks = tid >> 7;
        float acc = 0.f;
        int i0 = ks * 153;
        #pragma unroll 8
        for (int i = i0; i < i0 + 153; ++i)
            acc += s_g[i] * gW1[i * 128 + j];
        s_part[ks * 256 + j] = acc;
    }
    __syncthreads();
    if (tid < 128)
        s_gh[tid] = fmaxf(s_part[tid] + s_part[256 + tid] + gb1[tid], 0.f);
    __syncthreads();

    // phase 5: logits + top-2 softmax (wave 0)
    if (tid < 64) {
        float h0 = s_gh[tid], h1 = s_gh[tid + 64];
        float logit[NE];
        #pragma unroll
        for (int j = 0; j < NE; ++j) {
            float p = h0 * gW2[tid * NE + j] + h1 * gW2[(tid + 64) * NE + j];
            p = wave_reduce(p);
            logit[j] = p + gb2[j];
        }
        if (tid == 0) {
            int i1 = 0; float v1 = logit[0];
            #pragma unroll
            for (int i = 1; i < NE; ++i) if (logit[i] > v1) { v1 = logit[i]; i1 = i; }
            int i2 = -1; float v2 = -__builtin_inff();
            #pragma unroll
            for (int i = 0; i < NE; ++i) {
                if (i == i1) continue;
                if (logit[i] > v2) { v2 = logit[i]; i2 = i; }
            }
            float e2 = __expf(v2 - v1);
            float inv = 1.f / (1.f + e2);
            float out[NE] = {0.f, 0.f, 0.f, 0.f};
            out[i1] = inv; out[i2] = e2 * inv;
            #pragma unroll
            for (int i = 0; i < NE; ++i) ws[WS_GATES + b * NE + i] = out[i];
        }
    }
}

// ---------------------------------------------------------------------------
// K3: per (batch, gene-half): u for 2 active experts, then relu-dot epilogue.
// grid = 512 blocks of 256 threads.
// ---------------------------------------------------------------------------
__global__ __launch_bounds__(256) void k3_kernel(
    const float* __restrict__ eW1, const float* __restrict__ eb1,
    const float* __restrict__ eW2, const float* __restrict__ eb2,
    const float* __restrict__ ws, float* __restrict__ pred)
{
    __shared__ float s_g[GLOBAL_F];
    __shared__ float s_u[2 * 128];
    __shared__ float s_w2[2 * 128];

    const int b = blockIdx.x >> 1, half = blockIdx.x & 1, tid = threadIdx.x;

    // stage g  (BUGFIX r5->r6: s_g[256..305] was never written — 306 > 256)
    if (tid < 128) {
        float a = ws[WS_PDRUG + (0 * NB + b) * 128 + tid]
                + ws[WS_PDRUG + (1 * NB + b) * 128 + tid]
                + ws[WS_PDRUG + (2 * NB + b) * 128 + tid]
                + ws[WS_PDRUG + (3 * NB + b) * 128 + tid];
        s_g[tid] = a;
    } else if (tid < 178) {
        s_g[tid] = ws[WS_CELL + b * 50 + (tid - 128)];
    } else {
        s_g[tid] = ws[WS_DOSE + b * 128 + (tid - 178)];   // dose[0..77]
    }
    if (tid < GLOBAL_F - 256)                              // dose[78..127]
        s_g[256 + tid] = ws[WS_DOSE + b * 128 + 78 + tid];

    // gates (all threads, uniform)
    float g0 = ws[WS_GATES + b * NE + 0], g1 = ws[WS_GATES + b * NE + 1];
    float g2 = ws[WS_GATES + b * NE + 2], g3 = ws[WS_GATES + b * NE + 3];
    float gv[NE] = {g0, g1, g2, g3};
    int e1 = -1, e2 = -1;
    #pragma unroll
    for (int i = 0; i < NE; ++i)
        if (gv[i] > 0.f) { if (e1 < 0) e1 = i; else e2 = i; }
    if (e1 < 0) e1 = 0;
    if (e2 < 0) e2 = (e1 + 1) & 3;          // safety (never expected)
    const float gA = gv[e1], gB = gv[e2];
    __syncthreads();

    // u for the two active experts (306 iters, lane-coalesced weight reads)
    {
        int es = tid >> 7, h = tid & 127;
        int e = es ? e2 : e1;
        float acc = eb1[e * 128 + h];
        #pragma unroll 8
        for (int i = 0; i < GLOBAL_F; ++i)
            acc += s_g[i] * eW1[((size_t)e * EXP_IN + i) * 128 + h];
        s_u[es * 128 + h] = acc;
        s_w2[es * 128 + h] = eW2[e * 128 + h];
    }
    const float bA = eb2[e1], bB = eb2[e2];
    __syncthreads();

    // epilogue over this half's genes
    const float* v = ws + WS_V;
    const int g_lo = half * 489;
    for (int gg = g_lo + tid; gg < g_lo + 489; gg += 256) {
        const float4* vA = (const float4*)(v + ((size_t)(gg * NE + e1)) * 128);
        const float4* vB = (const float4*)(v + ((size_t)(gg * NE + e2)) * 128);
        float dA = 0.f, dB = 0.f;
        #pragma unroll 8
        for (int k = 0; k < 32; ++k) {
            float4 va = vA[k], vb = vB[k];
            dA += fmaxf(s_u[4*k+0] + va.x, 0.f) * s_w2[4*k+0]
                + fmaxf(s_u[4*k+1] + va.y, 0.f) * s_w2[4*k+1]
                + fmaxf(s_u[4*k+2] + va.z, 0.f) * s_w2[4*k+2]
                + fmaxf(s_u[4*k+3] + va.w, 0.f) * s_w2[4*k+3];
            dB += fmaxf(s_u[128+4*k+0] + vb.x, 0.f) * s_w2[128+4*k+0]
                + fmaxf(s_u[128+4*k+1] + vb.y, 0.f) * s_w2[128+4*k+1]
                + fmaxf(s_u[128+4*k+2] + vb.z, 0.f) * s_w2[128+4*k+2]
                + fmaxf(s_u[128+4*k+3] + vb.w, 0.f) * s_w2[128+4*k+3];
        }
        pred[b * NG + gg] = gA * (dA + bA) + gB * (dB + bB);
    }
}

// ---------------------------------------------------------------------------
extern "C" void kernel_launch(void* const* d_in, const int* in_sizes, int n_in,
                              void* d_out, int out_size, void* d_ws, size_t ws_size,
                              hipStream_t stream) {
    const float* drug  = (const float*)d_in[0];
    const float* gex   = (const float*)d_in[1];
    const float* idose = (const float*)d_in[2];
    const float* cW1 = (const float*)d_in[3];  const float* cb1 = (const float*)d_in[4];
    const float* cW2 = (const float*)d_in[5];  const float* cb2 = (const float*)d_in[6];
    const float* cW3 = (const float*)d_in[7];  const float* cb3 = (const float*)d_in[8];
    const float* dW1 = (const float*)d_in[9];  const float* db1 = (const float*)d_in[10];
    const float* dW2 = (const float*)d_in[11]; const float* db2 = (const float*)d_in[12];
    const float* gene = (const float*)d_in[13];
    const float* gW1 = (const float*)d_in[14]; const float* gb1 = (const float*)d_in[15];
    const float* gW2 = (const float*)d_in[16]; const float* gb2 = (const float*)d_in[17];
    const float* eW1 = (const float*)d_in[18]; const float* eb1 = (const float*)d_in[19];
    const float* eW2 = (const float*)d_in[20]; const float* eb2 = (const float*)d_in[21];

    float* ws   = (float*)d_ws;
    float* out  = (float*)d_out;
    float* pred = out;               // [B, G]
    float* cell = out + NB * NG;     // [B, 50]

    k1_kernel<<<K1_GRID, 256, K1_DYN_LDS, stream>>>(
        gene, eW1, drug, idose, dW1, db1, dW2, db2, ws);
    k2_kernel<<<NB, 512, 0, stream>>>(
        gex, cW1, cb1, cW2, cb2, cW3, cb3, gW1, gb1, gW2, gb2, ws, cell);
    k3_kernel<<<NB * 2, 256, 0, stream>>>(eW1, eb1, eW2, eb2, ws, pred);
}

// Round 7
// 176.071 us; speedup vs baseline: 1.5187x; 1.4444x over previous
//
#include <hip/hip_runtime.h>

#define NB 256
#define NA 64
#define NG 978
#define CELL_IN 978
#define DOSE_IN 12
#define GLOBAL_F 306
#define EXP_IN 434
#define NE 4

// ---- workspace layout (float offsets) ----
#define WS_GATES 0                        // [256*4]
#define WS_U     (WS_GATES + NB*NE)       // [256][4][128]
#define WS_V     (WS_U + NB*NE*128)       // [978][4][128]
// total ~633k floats ~2.5 MB

__device__ __forceinline__ float wave_reduce(float p) {
    #pragma unroll
    for (int off = 32; off > 0; off >>= 1) p += __shfl_down(p, off, 64);
    return p;
}

// ---------------------------------------------------------------------------
// A: v[g,e,h] = gene[g,:128] @ eW1[e,306+k,h].  One gene per block.
// thread = (e<4, ks<2, h4<32); 64-iter float4 chains; 2-way K partials in LDS.
// ---------------------------------------------------------------------------
__global__ __launch_bounds__(256) void a_kernel(
    const float* __restrict__ gene, const float* __restrict__ eW1,
    float* __restrict__ ws)
{
    __shared__ float s_gene[128];
    __shared__ float s_p[4 * 2 * 128];    // [e][ks][h]
    const int g = blockIdx.x, tid = threadIdx.x;

    if (tid < 128) s_gene[tid] = gene[g * 128 + tid];
    __syncthreads();

    const int e = tid >> 6, ks = (tid >> 5) & 1, h4 = tid & 31;
    const float* wp = eW1 + ((size_t)e * EXP_IN + GLOBAL_F) * 128 + 4 * h4;
    float4 acc = {0.f, 0.f, 0.f, 0.f};
    const int k0 = ks * 64;
    #pragma unroll 8
    for (int k = k0; k < k0 + 64; ++k) {
        float4 w = *(const float4*)(wp + (size_t)k * 128);
        float x = s_gene[k];
        acc.x += x * w.x; acc.y += x * w.y; acc.z += x * w.z; acc.w += x * w.w;
    }
    *(float4*)(s_p + (e * 2 + ks) * 128 + 4 * h4) = acc;
    __syncthreads();

    if (tid < 128) {                      // 128 float4 outputs = 512 floats
        int oe = tid >> 5, oh4 = tid & 31;
        float4 p0 = *(const float4*)(s_p + (oe * 2 + 0) * 128 + 4 * oh4);
        float4 p1 = *(const float4*)(s_p + (oe * 2 + 1) * 128 + 4 * oh4);
        float4 o = {p0.x + p1.x, p0.y + p1.y, p0.z + p1.z, p0.w + p1.w};
        *(float4*)(ws + WS_V + (size_t)g * 512 + oe * 128 + 4 * oh4) = o;
    }
}

// ---------------------------------------------------------------------------
// B: entire per-batch pipeline. 256 blocks x 1024 threads (16 waves/CU).
// drug sum, dose MLP, cell 978->200->100->50 (16-way K-split, float4),
// gate MLP + top-2 softmax, u for all 4 experts (8-way K-split, float4).
// ---------------------------------------------------------------------------
__global__ __launch_bounds__(1024) void b_kernel(
    const float* __restrict__ drug, const float* __restrict__ gex,
    const float* __restrict__ idose,
    const float* __restrict__ cW1, const float* __restrict__ cb1,
    const float* __restrict__ cW2, const float* __restrict__ cb2,
    const float* __restrict__ cW3, const float* __restrict__ cb3,
    const float* __restrict__ dW1, const float* __restrict__ db1,
    const float* __restrict__ dW2, const float* __restrict__ db2,
    const float* __restrict__ gW1, const float* __restrict__ gb1,
    const float* __restrict__ gW2, const float* __restrict__ gb2,
    const float* __restrict__ eW1, const float* __restrict__ eb1,
    float* __restrict__ ws, float* __restrict__ cell_out)
{
    __shared__ float s_gex[CELL_IN];
    __shared__ float s_g[GLOBAL_F];
    __shared__ float s_h1[200];
    __shared__ float s_h2[100];
    __shared__ float s_gh[128];
    __shared__ float s_d1[64];
    __shared__ float s_part[16 * 200];    // K-split partials (reused)
    __shared__ float s_pu[8 * 512];       // u partials + drug scratch

    const int b = blockIdx.x, tid = threadIdx.x;

    // ---- P0: stage gex; drug partials; dose layer1 ----
    if (tid < CELL_IN) s_gex[tid] = gex[b * CELL_IN + tid];
    {
        int row = tid >> 7, d = tid & 127;       // 8 rows x 128
        const float* p = drug + ((size_t)b * NA) * 128 + d;
        float acc = 0.f;
        #pragma unroll
        for (int i = 0; i < 8; ++i) acc += p[(size_t)(i * 8 + row) * 128];
        s_pu[row * 128 + d] = acc;
    }
    __syncthreads();
    if (tid < 128) {
        float a = 0.f;
        #pragma unroll
        for (int r = 0; r < 8; ++r) a += s_pu[r * 128 + tid];
        s_g[tid] = a;
    } else if (tid < 192) {
        int j = tid - 128;
        float acc = db1[j];
        #pragma unroll
        for (int i = 0; i < DOSE_IN; ++i)
            acc += idose[b * DOSE_IN + i] * dW1[i * 64 + j];
        s_d1[j] = fmaxf(acc, 0.f);
    }
    __syncthreads();
    // ---- P0d: dose layer2 ----
    if (tid < 128) {
        float acc = db2[tid];
        #pragma unroll 8
        for (int i = 0; i < 64; ++i) acc += s_d1[i] * dW2[i * 128 + tid];
        s_g[178 + tid] = fmaxf(acc, 0.f);
    }
    __syncthreads();

    // ---- P1: cell1 978->200, 16-way K-split, float4 outputs ----
    {
        int q = tid & 63, ks = tid >> 6;         // q<50 active, ks 0..15
        if (q < 50) {
            int i0 = ks * 62, i1 = min(i0 + 62, CELL_IN);
            float4 acc = {0.f, 0.f, 0.f, 0.f};
            #pragma unroll 4
            for (int i = i0; i < i1; ++i) {
                float4 w = *(const float4*)(cW1 + (size_t)i * 200 + 4 * q);
                float x = s_gex[i];
                acc.x += x * w.x; acc.y += x * w.y; acc.z += x * w.z; acc.w += x * w.w;
            }
            *(float4*)(s_part + ks * 200 + 4 * q) = acc;
        }
    }
    __syncthreads();
    if (tid < 200) {
        float a = cb1[tid];
        #pragma unroll
        for (int ks = 0; ks < 16; ++ks) a += s_part[ks * 200 + tid];
        s_h1[tid] = fmaxf(a, 0.f);
    }
    __syncthreads();

    // ---- P2: cell2 200->100, 16-way K-split, float4 ----
    {
        int q = tid & 31, ks = tid >> 5;         // q<25 active, ks<16
        if (q < 25 && ks < 16) {
            int i0 = ks * 13, i1 = min(i0 + 13, 200);
            float4 acc = {0.f, 0.f, 0.f, 0.f};
            #pragma unroll
            for (int i = i0; i < i1; ++i) {
                float4 w = *(const float4*)(cW2 + (size_t)i * 100 + 4 * q);
                float x = s_h1[i];
                acc.x += x * w.x; acc.y += x * w.y; acc.z += x * w.z; acc.w += x * w.w;
            }
            *(float4*)(s_part + ks * 100 + 4 * q) = acc;
        }
    }
    __syncthreads();
    if (tid < 100) {
        float a = cb2[tid];
        #pragma unroll
        for (int ks = 0; ks < 16; ++ks) a += s_part[ks * 100 + tid];
        s_h2[tid] = fmaxf(a, 0.f);
    }
    __syncthreads();

    // ---- P3: cell3 100->50, 8-way K-split, scalar ----
    {
        int j = tid & 63, ks = tid >> 6;         // j<50, ks<8
        if (j < 50 && ks < 8) {
            int i0 = ks * 13, i1 = min(i0 + 13, 100);
            float acc = 0.f;
            #pragma unroll
            for (int i = i0; i < i1; ++i) acc += s_h2[i] * cW3[i * 50 + j];
            s_part[ks * 64 + j] = acc;
        }
    }
    __syncthreads();
    if (tid < 50) {
        float a = cb3[tid];
        #pragma unroll
        for (int ks = 0; ks < 8; ++ks) a += s_part[ks * 64 + tid];
        float r = fmaxf(a, 0.f);
        s_g[128 + tid] = r;
        cell_out[b * 50 + tid] = r;
    }
    __syncthreads();

    // ---- P4: gate1 306->128, 16-way K-split, float4 ----
    {
        int q = tid & 31, ks = tid >> 5;         // q<32, ks<16
        if (ks < 16) {
            int i0 = ks * 20, i1 = min(i0 + 20, GLOBAL_F);
            float4 acc = {0.f, 0.f, 0.f, 0.f};
            #pragma unroll
            for (int i = i0; i < i1; ++i) {
                float4 w = *(const float4*)(gW1 + (size_t)i * 128 + 4 * q);
                float x = s_g[i];
                acc.x += x * w.x; acc.y += x * w.y; acc.z += x * w.z; acc.w += x * w.w;
            }
            *(float4*)(s_part + ks * 128 + 4 * q) = acc;
        }
    }
    __syncthreads();
    if (tid < 128) {
        float a = gb1[tid];
        #pragma unroll
        for (int ks = 0; ks < 16; ++ks) a += s_part[ks * 128 + tid];
        s_gh[tid] = fmaxf(a, 0.f);
    }
    __syncthreads();

    // ---- P5: logits + top-2 softmax -> ws gates ----
    if (tid < 64) {
        float h0 = s_gh[tid], h1 = s_gh[tid + 64];
        float logit[NE];
        #pragma unroll
        for (int j = 0; j < NE; ++j) {
            float p = h0 * gW2[tid * NE + j] + h1 * gW2[(tid + 64) * NE + j];
            p = wave_reduce(p);
            logit[j] = p + gb2[j];
        }
        if (tid == 0) {
            int i1 = 0; float v1 = logit[0];
            #pragma unroll
            for (int i = 1; i < NE; ++i) if (logit[i] > v1) { v1 = logit[i]; i1 = i; }
            int i2 = -1; float v2 = -__builtin_inff();
            #pragma unroll
            for (int i = 0; i < NE; ++i) {
                if (i == i1) continue;
                if (logit[i] > v2) { v2 = logit[i]; i2 = i; }
            }
            float e2 = __expf(v2 - v1);
            float inv = 1.f / (1.f + e2);
            float out[NE] = {0.f, 0.f, 0.f, 0.f};
            out[i1] = inv; out[i2] = e2 * inv;
            #pragma unroll
            for (int i = 0; i < NE; ++i) ws[WS_GATES + b * NE + i] = out[i];
        }
    }
    __syncthreads();

    // ---- P6: u[b,e,h] for all 4 experts, 8-way K-split, float4 ----
    {
        int e = tid >> 8, ks = (tid >> 5) & 7, h4 = tid & 31;   // 4*8*32 = 1024
        int i0 = ks * 39, i1 = min(i0 + 39, GLOBAL_F);
        const float* wp = eW1 + (size_t)e * EXP_IN * 128 + 4 * h4;
        float4 acc = {0.f, 0.f, 0.f, 0.f};
        #pragma unroll 4
        for (int i = i0; i < i1; ++i) {
            float4 w = *(const float4*)(wp + (size_t)i * 128);
            float x = s_g[i];
            acc.x += x * w.x; acc.y += x * w.y; acc.z += x * w.z; acc.w += x * w.w;
        }
        *(float4*)(s_pu + (e * 8 + ks) * 128 + 4 * h4) = acc;
    }
    __syncthreads();
    if (tid < 128) {                      // 128 float4 = 512 outputs
        int e = tid >> 5, h4 = tid & 31;
        float4 a = *(const float4*)(eb1 + e * 128 + 4 * h4);
        #pragma unroll
        for (int ks = 0; ks < 8; ++ks) {
            float4 p = *(const float4*)(s_pu + (e * 8 + ks) * 128 + 4 * h4);
            a.x += p.x; a.y += p.y; a.z += p.z; a.w += p.w;
        }
        *(float4*)(ws + WS_U + (size_t)b * 512 + e * 128 + 4 * h4) = a;
    }
}

// ---------------------------------------------------------------------------
// C: epilogue. 1024 blocks = (b, quarter); one gene per thread.
// pred[b,g] = sum_{active e} gate_e * (dot(relu(u[b,e]+v[g,e]), w2[e]) + b2[e])
// ---------------------------------------------------------------------------
__global__ __launch_bounds__(256) void c_kernel(
    const float* __restrict__ eW2, const float* __restrict__ eb2,
    const float* __restrict__ ws, float* __restrict__ pred)
{
    __shared__ float s_u[2 * 128];
    __shared__ float s_w2[2 * 128];
    const int b = blockIdx.x >> 2, qt = blockIdx.x & 3, tid = threadIdx.x;

    float g0 = ws[WS_GATES + b * NE + 0], g1 = ws[WS_GATES + b * NE + 1];
    float g2 = ws[WS_GATES + b * NE + 2], g3 = ws[WS_GATES + b * NE + 3];
    float gv[NE] = {g0, g1, g2, g3};
    int e1 = -1, e2 = -1;
    #pragma unroll
    for (int i = 0; i < NE; ++i)
        if (gv[i] > 0.f) { if (e1 < 0) e1 = i; else e2 = i; }
    if (e1 < 0) e1 = 0;
    if (e2 < 0) e2 = (e1 + 1) & 3;
    const float gA = gv[e1], gB = gv[e2];
    const float bA = eb2[e1], bB = eb2[e2];

    if (tid < 256) {
        int es = tid >> 7, h = tid & 127;
        int e = es ? e2 : e1;
        s_u[es * 128 + h] = ws[WS_U + (size_t)b * 512 + e * 128 + h];
        s_w2[es * 128 + h] = eW2[e * 128 + h];
    }
    __syncthreads();

    const int g = qt * 245 + tid;
    if (tid < 245 && g < NG) {
        const float4* vA = (const float4*)(ws + WS_V + (size_t)g * 512 + e1 * 128);
        const float4* vB = (const float4*)(ws + WS_V + (size_t)g * 512 + e2 * 128);
        float dA = 0.f, dB = 0.f;
        #pragma unroll 8
        for (int k = 0; k < 32; ++k) {
            float4 va = vA[k], vb = vB[k];
            dA += fmaxf(s_u[4*k+0] + va.x, 0.f) * s_w2[4*k+0]
                + fmaxf(s_u[4*k+1] + va.y, 0.f) * s_w2[4*k+1]
                + fmaxf(s_u[4*k+2] + va.z, 0.f) * s_w2[4*k+2]
                + fmaxf(s_u[4*k+3] + va.w, 0.f) * s_w2[4*k+3];
            dB += fmaxf(s_u[128+4*k+0] + vb.x, 0.f) * s_w2[128+4*k+0]
                + fmaxf(s_u[128+4*k+1] + vb.y, 0.f) * s_w2[128+4*k+1]
                + fmaxf(s_u[128+4*k+2] + vb.z, 0.f) * s_w2[128+4*k+2]
                + fmaxf(s_u[128+4*k+3] + vb.w, 0.f) * s_w2[128+4*k+3];
        }
        pred[b * NG + g] = gA * (dA + bA) + gB * (dB + bB);
    }
}

// ---------------------------------------------------------------------------
extern "C" void kernel_launch(void* const* d_in, const int* in_sizes, int n_in,
                              void* d_out, int out_size, void* d_ws, size_t ws_size,
                              hipStream_t stream) {
    const float* drug  = (const float*)d_in[0];
    const float* gex   = (const float*)d_in[1];
    const float* idose = (const float*)d_in[2];
    const float* cW1 = (const float*)d_in[3];  const float* cb1 = (const float*)d_in[4];
    const float* cW2 = (const float*)d_in[5];  const float* cb2 = (const float*)d_in[6];
    const float* cW3 = (const float*)d_in[7];  const float* cb3 = (const float*)d_in[8];
    const float* dW1 = (const float*)d_in[9];  const float* db1 = (const float*)d_in[10];
    const float* dW2 = (const float*)d_in[11]; const float* db2 = (const float*)d_in[12];
    const float* gene = (const float*)d_in[13];
    const float* gW1 = (const float*)d_in[14]; const float* gb1 = (const float*)d_in[15];
    const float* gW2 = (const float*)d_in[16]; const float* gb2 = (const float*)d_in[17];
    const float* eW1 = (const float*)d_in[18]; const float* eb1 = (const float*)d_in[19];
    const float* eW2 = (const float*)d_in[20]; const float* eb2 = (const float*)d_in[21];

    float* ws   = (float*)d_ws;
    float* out  = (float*)d_out;
    float* pred = out;               // [B, G]
    float* cell = out + NB * NG;     // [B, 50]

    a_kernel<<<NG, 256, 0, stream>>>(gene, eW1, ws);
    b_kernel<<<NB, 1024, 0, stream>>>(drug, gex, idose,
        cW1, cb1, cW2, cb2, cW3, cb3, dW1, db1, dW2, db2,
        gW1, gb1, gW2, gb2, eW1, eb1, ws, cell);
    c_kernel<<<NB * 4, 256, 0, stream>>>(eW2, eb2, ws, pred);
}

// Round 8
// 167.304 us; speedup vs baseline: 1.5983x; 1.0524x over previous
//
#include <hip/hip_runtime.h>

#define NB 256
#define NA 64
#define NG 978
#define CELL_IN 978
#define DOSE_IN 12
#define GLOBAL_F 306
#define EXP_IN 434
#define NE 4

// ---- workspace layout (float offsets) ----
#define WS_SEL 0                      // [256][4] : e1, e2, gate1, gate2
#define WS_U   (WS_SEL + NB*4)        // [256][2][128] u for the 2 active experts
#define WS_V   (WS_U + NB*256)        // [978][512]  v[g][e*128+h]
// total ~567k floats ~2.3 MB

#define AB_GRID (NB + 245)            // 256 b-blocks + 245 a-blocks (4 genes each)

__device__ __forceinline__ float wave_reduce(float p) {
    #pragma unroll
    for (int off = 32; off > 0; off >>= 1) p += __shfl_down(p, off, 64);
    return p;
}

// ---------------------------------------------------------------------------
// AB: blocks [0,256): full per-batch pipeline (drug/dose/cell/gate/top2/u).
//     blocks [256,501): v[g,e,h] = gene[g,:] @ eW1[e,306:,:]  (4 genes/block)
// 1024 threads; ~51 KB LDS -> 2 blocks/CU -> all 501 blocks co-resident.
// ---------------------------------------------------------------------------
__global__ __launch_bounds__(1024) void ab_kernel(
    const float* __restrict__ drug, const float* __restrict__ gex,
    const float* __restrict__ idose,
    const float* __restrict__ cW1, const float* __restrict__ cb1,
    const float* __restrict__ cW2, const float* __restrict__ cb2,
    const float* __restrict__ cW3, const float* __restrict__ cb3,
    const float* __restrict__ dW1, const float* __restrict__ db1,
    const float* __restrict__ dW2, const float* __restrict__ db2,
    const float* __restrict__ gW1, const float* __restrict__ gb1,
    const float* __restrict__ gW2, const float* __restrict__ gb2,
    const float* __restrict__ eW1, const float* __restrict__ eb1,
    const float* __restrict__ gene,
    float* __restrict__ ws, float* __restrict__ cell_out)
{
    __shared__ float s_gex[CELL_IN];
    __shared__ float s_g[GLOBAL_F];
    __shared__ float s_h1[200];
    __shared__ float s_h2[100];
    __shared__ float s_gh[128];
    __shared__ float s_d1[64];
    __shared__ int   s_isel[2];
    __shared__ float s_part[16 * 200];
    __shared__ float s_pu[32 * 128];
    __shared__ float s_ag[4][128];
    __shared__ float s_ap[4][8][128];

    const int blk = blockIdx.x, tid = threadIdx.x;

    if (blk >= NB) {
        // ================= a-part: v GEMM, 4 genes per block ===============
        const int gq = tid >> 8, lt = tid & 255;
        const int g = (blk - NB) * 4 + gq;
        if (lt < 128) s_ag[gq][lt] = (g < NG) ? gene[g * 128 + lt] : 0.f;
        __syncthreads();
        const int e = lt >> 6, ks = (lt >> 5) & 1, h4 = lt & 31;
        const float* wp = eW1 + ((size_t)e * EXP_IN + GLOBAL_F) * 128 + 4 * h4;
        float4 acc = {0.f, 0.f, 0.f, 0.f};
        const int k0 = ks * 64;
        #pragma unroll 8
        for (int k = k0; k < k0 + 64; ++k) {
            float4 w = *(const float4*)(wp + (size_t)k * 128);
            float x = s_ag[gq][k];
            acc.x += x * w.x; acc.y += x * w.y; acc.z += x * w.z; acc.w += x * w.w;
        }
        *(float4*)(&s_ap[gq][e * 2 + ks][4 * h4]) = acc;
        __syncthreads();
        if (lt < 128 && g < NG) {
            int oe = lt >> 5, oh4 = lt & 31;
            float4 p0 = *(const float4*)(&s_ap[gq][oe * 2 + 0][4 * oh4]);
            float4 p1 = *(const float4*)(&s_ap[gq][oe * 2 + 1][4 * oh4]);
            float4 o = {p0.x + p1.x, p0.y + p1.y, p0.z + p1.z, p0.w + p1.w};
            *(float4*)(ws + WS_V + (size_t)g * 512 + oe * 128 + 4 * oh4) = o;
        }
        return;
    }

    // ==================== b-part: per-batch pipeline =======================
    const int b = blk;

    // ---- P0: stage gex; drug partials; dose layer1 ----
    if (tid < CELL_IN) s_gex[tid] = gex[b * CELL_IN + tid];
    {
        int row = tid >> 7, d = tid & 127;
        const float* p = drug + ((size_t)b * NA) * 128 + d;
        float acc = 0.f;
        #pragma unroll
        for (int i = 0; i < 8; ++i) acc += p[(size_t)(i * 8 + row) * 128];
        s_pu[row * 128 + d] = acc;
    }
    __syncthreads();
    if (tid < 128) {
        float a = 0.f;
        #pragma unroll
        for (int r = 0; r < 8; ++r) a += s_pu[r * 128 + tid];
        s_g[tid] = a;
    } else if (tid < 192) {
        int j = tid - 128;
        float acc = db1[j];
        #pragma unroll
        for (int i = 0; i < DOSE_IN; ++i)
            acc += idose[b * DOSE_IN + i] * dW1[i * 64 + j];
        s_d1[j] = fmaxf(acc, 0.f);
    }
    __syncthreads();
    if (tid < 128) {
        float acc = db2[tid];
        #pragma unroll 8
        for (int i = 0; i < 64; ++i) acc += s_d1[i] * dW2[i * 128 + tid];
        s_g[178 + tid] = fmaxf(acc, 0.f);
    }
    __syncthreads();

    // ---- P1: cell1 978->200, 16-way K-split, float4 ----
    {
        int q = tid & 63, ks = tid >> 6;
        if (q < 50) {
            int i0 = ks * 62, i1 = min(i0 + 62, CELL_IN);
            float4 acc = {0.f, 0.f, 0.f, 0.f};
            #pragma unroll 4
            for (int i = i0; i < i1; ++i) {
                float4 w = *(const float4*)(cW1 + (size_t)i * 200 + 4 * q);
                float x = s_gex[i];
                acc.x += x * w.x; acc.y += x * w.y; acc.z += x * w.z; acc.w += x * w.w;
            }
            *(float4*)(&s_part[ks * 200 + 4 * q]) = acc;
        }
    }
    __syncthreads();
    if (tid < 200) {
        float a = cb1[tid];
        #pragma unroll
        for (int ks = 0; ks < 16; ++ks) a += s_part[ks * 200 + tid];
        s_h1[tid] = fmaxf(a, 0.f);
    }
    __syncthreads();

    // ---- P2: cell2 200->100, 16-way K-split, float4 ----
    {
        int q = tid & 31, ks = tid >> 5;
        if (q < 25 && ks < 16) {
            int i0 = ks * 13, i1 = min(i0 + 13, 200);
            float4 acc = {0.f, 0.f, 0.f, 0.f};
            #pragma unroll
            for (int i = i0; i < i1; ++i) {
                float4 w = *(const float4*)(cW2 + (size_t)i * 100 + 4 * q);
                float x = s_h1[i];
                acc.x += x * w.x; acc.y += x * w.y; acc.z += x * w.z; acc.w += x * w.w;
            }
            *(float4*)(&s_part[ks * 100 + 4 * q]) = acc;
        }
    }
    __syncthreads();
    if (tid < 100) {
        float a = cb2[tid];
        #pragma unroll
        for (int ks = 0; ks < 16; ++ks) a += s_part[ks * 100 + tid];
        s_h2[tid] = fmaxf(a, 0.f);
    }
    __syncthreads();

    // ---- P3: cell3 100->50, 8-way K-split ----
    {
        int j = tid & 63, ks = tid >> 6;
        if (j < 50 && ks < 8) {
            int i0 = ks * 13, i1 = min(i0 + 13, 100);
            float acc = 0.f;
            #pragma unroll
            for (int i = i0; i < i1; ++i) acc += s_h2[i] * cW3[i * 50 + j];
            s_part[ks * 64 + j] = acc;
        }
    }
    __syncthreads();
    if (tid < 50) {
        float a = cb3[tid];
        #pragma unroll
        for (int ks = 0; ks < 8; ++ks) a += s_part[ks * 64 + tid];
        float r = fmaxf(a, 0.f);
        s_g[128 + tid] = r;
        cell_out[b * 50 + tid] = r;
    }
    __syncthreads();

    // ---- P4: gate1 306->128, 16-way K-split, float4 ----
    {
        int q = tid & 31, ks = tid >> 5;
        if (ks < 16) {
            int i0 = ks * 20, i1 = min(i0 + 20, GLOBAL_F);
            float4 acc = {0.f, 0.f, 0.f, 0.f};
            #pragma unroll
            for (int i = i0; i < i1; ++i) {
                float4 w = *(const float4*)(gW1 + (size_t)i * 128 + 4 * q);
                float x = s_g[i];
                acc.x += x * w.x; acc.y += x * w.y; acc.z += x * w.z; acc.w += x * w.w;
            }
            *(float4*)(&s_part[ks * 128 + 4 * q]) = acc;
        }
    }
    __syncthreads();
    if (tid < 128) {
        float a = gb1[tid];
        #pragma unroll
        for (int ks = 0; ks < 16; ++ks) a += s_part[ks * 128 + tid];
        s_gh[tid] = fmaxf(a, 0.f);
    }
    __syncthreads();

    // ---- P5: logits + top-2 softmax -> s_isel, ws sel ----
    if (tid < 64) {
        float h0 = s_gh[tid], h1 = s_gh[tid + 64];
        float logit[NE];
        #pragma unroll
        for (int j = 0; j < NE; ++j) {
            float p = h0 * gW2[tid * NE + j] + h1 * gW2[(tid + 64) * NE + j];
            p = wave_reduce(p);
            logit[j] = p + gb2[j];
        }
        if (tid == 0) {
            int i1 = 0; float v1 = logit[0];
            #pragma unroll
            for (int i = 1; i < NE; ++i) if (logit[i] > v1) { v1 = logit[i]; i1 = i; }
            int i2 = -1; float v2 = -__builtin_inff();
            #pragma unroll
            for (int i = 0; i < NE; ++i) {
                if (i == i1) continue;
                if (logit[i] > v2) { v2 = logit[i]; i2 = i; }
            }
            float ex = __expf(v2 - v1);
            float inv = 1.f / (1.f + ex);
            s_isel[0] = i1; s_isel[1] = i2;
            ws[WS_SEL + b * 4 + 0] = (float)i1;
            ws[WS_SEL + b * 4 + 1] = (float)i2;
            ws[WS_SEL + b * 4 + 2] = inv;
            ws[WS_SEL + b * 4 + 3] = ex * inv;
        }
    }
    __syncthreads();

    // ---- P6: u for the 2 ACTIVE experts, 16-way K-split, float4 ----
    {
        int es = tid >> 9, ks = (tid >> 5) & 15, h4 = tid & 31;
        int e = s_isel[es];
        int i0 = ks * 20, i1 = min(i0 + 20, GLOBAL_F);
        const float* wp = eW1 + (size_t)e * EXP_IN * 128 + 4 * h4;
        float4 acc = {0.f, 0.f, 0.f, 0.f};
        #pragma unroll
        for (int i = i0; i < i1; ++i) {
            float4 w = *(const float4*)(wp + (size_t)i * 128);
            float x = s_g[i];
            acc.x += x * w.x; acc.y += x * w.y; acc.z += x * w.z; acc.w += x * w.w;
        }
        *(float4*)(&s_pu[(es * 16 + ks) * 128 + 4 * h4]) = acc;
    }
    __syncthreads();
    if (tid < 256) {
        int es = tid >> 7, h = tid & 127;
        int e = s_isel[es];
        float a = eb1[e * 128 + h];
        #pragma unroll
        for (int ks = 0; ks < 16; ++ks) a += s_pu[(es * 16 + ks) * 128 + h];
        ws[WS_U + (size_t)b * 256 + es * 128 + h] = a;
    }
}

// ---------------------------------------------------------------------------
// C: epilogue, tiled (16 batches x 28 genes)/block, everything staged in LDS.
// grid = 16 batch-tiles x 35 gene-tiles = 560 blocks, 256 threads.
// ---------------------------------------------------------------------------
#define GT 28
#define BT 16
__global__ __launch_bounds__(256) void c_kernel(
    const float* __restrict__ eW2, const float* __restrict__ eb2,
    const float* __restrict__ ws, float* __restrict__ pred)
{
    __shared__ float s_v[GT * 520];   // padded stride: bank-spread
    __shared__ float s_u[BT * 260];
    __shared__ float s_w2[512];
    __shared__ float s_sel[BT * 4];
    const int bt = blockIdx.x & 15, gt = blockIdx.x >> 4, tid = threadIdx.x;
    const int b0 = bt * BT, g0 = gt * GT;

    if (tid < BT * 4) s_sel[tid] = ws[WS_SEL + b0 * 4 + tid];
    for (int i = tid; i < 512; i += 256) s_w2[i] = eW2[i];
    for (int i4 = tid; i4 < BT * 64; i4 += 256) {
        int bl = i4 >> 6, h4 = i4 & 63;
        float4 u = *(const float4*)(ws + WS_U + (size_t)(b0 + bl) * 256 + 4 * h4);
        *(float4*)(&s_u[bl * 260 + 4 * h4]) = u;
    }
    for (int i4 = tid; i4 < GT * 128; i4 += 256) {
        int gl = i4 >> 7, h4 = i4 & 127;
        int g = g0 + gl;
        float4 v = {0.f, 0.f, 0.f, 0.f};
        if (g < NG) v = *(const float4*)(ws + WS_V + (size_t)g * 512 + 4 * h4);
        *(float4*)(&s_v[gl * 520 + 4 * h4]) = v;
    }
    __syncthreads();

    const int bl = tid & 15;
    const int ea = (int)s_sel[bl * 4 + 0], eb = (int)s_sel[bl * 4 + 1];
    const float gA = s_sel[bl * 4 + 2], gB = s_sel[bl * 4 + 3];
    const float bA = eb2[ea], bB = eb2[eb];
    #pragma unroll
    for (int it = 0; it < 2; ++it) {
        int gl = (tid >> 4) + 16 * it;
        int g = g0 + gl;
        if (gl < GT && g < NG) {
            const float* vA = s_v + gl * 520 + ea * 128;
            const float* vB = s_v + gl * 520 + eb * 128;
            const float* uA = s_u + bl * 260;
            const float* uB = uA + 128;
            const float* wA = s_w2 + ea * 128;
            const float* wB = s_w2 + eb * 128;
            float dA = 0.f, dB = 0.f;
            #pragma unroll 8
            for (int k = 0; k < 32; ++k) {
                float4 va = *(const float4*)(vA + 4 * k);
                float4 ua = *(const float4*)(uA + 4 * k);
                float4 wa = *(const float4*)(wA + 4 * k);
                dA += fmaxf(ua.x + va.x, 0.f) * wa.x + fmaxf(ua.y + va.y, 0.f) * wa.y
                    + fmaxf(ua.z + va.z, 0.f) * wa.z + fmaxf(ua.w + va.w, 0.f) * wa.w;
                float4 vb = *(const float4*)(vB + 4 * k);
                float4 ub = *(const float4*)(uB + 4 * k);
                float4 wb = *(const float4*)(wB + 4 * k);
                dB += fmaxf(ub.x + vb.x, 0.f) * wb.x + fmaxf(ub.y + vb.y, 0.f) * wb.y
                    + fmaxf(ub.z + vb.z, 0.f) * wb.z + fmaxf(ub.w + vb.w, 0.f) * wb.w;
            }
            pred[(size_t)(b0 + bl) * NG + g] = gA * (dA + bA) + gB * (dB + bB);
        }
    }
}

// ---------------------------------------------------------------------------
extern "C" void kernel_launch(void* const* d_in, const int* in_sizes, int n_in,
                              void* d_out, int out_size, void* d_ws, size_t ws_size,
                              hipStream_t stream) {
    const float* drug  = (const float*)d_in[0];
    const float* gex   = (const float*)d_in[1];
    const float* idose = (const float*)d_in[2];
    const float* cW1 = (const float*)d_in[3];  const float* cb1 = (const float*)d_in[4];
    const float* cW2 = (const float*)d_in[5];  const float* cb2 = (const float*)d_in[6];
    const float* cW3 = (const float*)d_in[7];  const float* cb3 = (const float*)d_in[8];
    const float* dW1 = (const float*)d_in[9];  const float* db1 = (const float*)d_in[10];
    const float* dW2 = (const float*)d_in[11]; const float* db2 = (const float*)d_in[12];
    const float* gene = (const float*)d_in[13];
    const float* gW1 = (const float*)d_in[14]; const float* gb1 = (const float*)d_in[15];
    const float* gW2 = (const float*)d_in[16]; const float* gb2 = (const float*)d_in[17];
    const float* eW1 = (const float*)d_in[18]; const float* eb1 = (const float*)d_in[19];
    const float* eW2 = (const float*)d_in[20]; const float* eb2 = (const float*)d_in[21];

    float* ws   = (float*)d_ws;
    float* out  = (float*)d_out;
    float* pred = out;               // [B, G]
    float* cell = out + NB * NG;     // [B, 50]

    ab_kernel<<<AB_GRID, 1024, 0, stream>>>(drug, gex, idose,
        cW1, cb1, cW2, cb2, cW3, cb3, dW1, db1, dW2, db2,
        gW1, gb1, gW2, gb2, eW1, eb1, gene, ws, cell);
    c_kernel<<<16 * 35, 256, 0, stream>>>(eW2, eb2, ws, pred);
}